// Round 13
// baseline (118.118 us; speedup 1.0000x reference)
//
#include <hip/hip_runtime.h>

// B=8, C=64, H=W=64, CI=32, N=4096 pixels, M=1024 pooled.
// y[b,n,:] = (a_n*S1[k_n,:] + S2[k_n,:])/1024 ; only W_w . y is needed, so
// track U = Ww.psi (64-dim) and its sorted-order prefixes T1/T2 directly.
// BN stats from per-k scalars (cnt, sum a, sum a^2) x T rows - no Gram.
//
// r18: split at gen2. r12 banked P1-GEMM (kA ~36us, e2e 115.7). The
// remaining sc1 machinery is P3's bulk traffic: U 2MB sc1-write + 2MB
// sc1-gather (MALL latency, L2 defeated) + sc1 BB/RK/hist re-reads +
// the gen2 barrier. A kernel boundary's launch-acquire invalidates L2
// device-wide, so data written in kernel N (any class) is plain-readable
// in kernel N+1. New: kA1 = P1 + per-batch gen1 + P2 (U/RK plain stores,
// gen2 deleted); kA2 = P3 all-plain loads (BB/RK/hist shared by 32
// blocks/batch -> L2 reuse); kB unchanged. Numerics identical to r12.
#define OFF_A    0         // a[b][n]               : 32768 floats
#define OFF_BB   32768     // bb[b][m]              : 8192
#define OFF_RK   40960     // rank[b][m] (int)      : 8192
#define OFF_U    57344     // U_T[b][o][m]          : 8*64*1024 = 524288
#define OFF_T1   581632    // T1[b][k<=1024][o]     : 8*1025*64 = 524800
#define OFF_T2   1106432   // T2[b][k][o]           : 524800
#define OFF_KK   1631232   // k[b][n] (int)         : 32768
#define OFF_MP1  1664000   // moment1 partials [b][o] : 512
#define OFF_MP2  1664512   // moment2 partials [b][o] : 512
#define OFF_HC   1665024   // hist cnt[b][1025]     : 8200
#define OFF_HS   1673224   // hist sum_a[b][1025]   : 8200
#define OFF_HS2  1681424   // hist sum_a2[b][1025]  : 8200
#define OFF_BAR  1689624   // u32: batch b ctr @32*(b+1); flags @288,289

// Coherent (sc1, L2-bypass) helpers -- intra-kA1 cross-block data only.
__device__ __forceinline__ void stg(float* p, float v) {
    __hip_atomic_store(p, v, __ATOMIC_RELAXED, __HIP_MEMORY_SCOPE_AGENT);
}
__device__ __forceinline__ float ldg1(const float* p) {
    return __hip_atomic_load(p, __ATOMIC_RELAXED, __HIP_MEMORY_SCOPE_AGENT);
}
__device__ __forceinline__ void stgu(unsigned* p, unsigned v) {
    __hip_atomic_store(p, v, __ATOMIC_RELAXED, __HIP_MEMORY_SCOPE_AGENT);
}
__device__ __forceinline__ unsigned ldgu(const unsigned* p) {
    return __hip_atomic_load(p, __ATOMIC_RELAXED, __HIP_MEMORY_SCOPE_AGENT);
}

// kA1 LDS carve (floats), sh[12484] = 49.9 KB:
// P1 conv:  sX@0 (64c x 128px = 8192) sW@8192 (64c x 64f = 4096)
//           sth@12288 (68)  sA2@12356 (128, persists into P2)
// P1 epilo: spsi@0 (32x33) sphi@1056 (32x33) sWw@2112 (64x33) [sX dead]
// P2:       sb@0 (1024)
__global__ __launch_bounds__(1024) void kA1(
    const float* __restrict__ x, const float* __restrict__ theta_w,
    const float* __restrict__ theta_b, const float* __restrict__ phi_w,
    const float* __restrict__ phi_b, const float* __restrict__ psi_w,
    const float* __restrict__ psi_b, const float* __restrict__ cp_w,
    const float* __restrict__ Ww, float* __restrict__ ws)
{
    __shared__ __align__(16) float sh[12484];
    const int tid = threadIdx.x;
    const int bid = blockIdx.x;
    const int b   = bid >> 5;     // 32 blocks per batch image
    const int sub = bid & 31;
    unsigned* bars = (unsigned*)(ws + OFF_BAR);
    float* sX  = sh;
    float* sW  = sh + 8192;
    float* sth = sh + 12288;
    float* sA2 = sh + 12356;

    // ---------- Phase 1: conv (GEMM form) + pool -> bb, U_T ; theta -> a --
    {
        if (bid == 0 && tid == 0) {     // zero 8 batch counters (sc1)
            for (int i = 0; i < 8; ++i) stgu(&bars[(i + 1) << 5], 0u);
        }
        // zero this block's slice of ITS OWN batch's hist (sc1: target of
        // P2's MALL atomics, read plain by kA2 after the boundary).
        if (tid < 97) {
            int e = sub*97 + tid;
            if (e < 1025)      stg(&ws[OFF_HC  + b*1025 + e], 0.0f);
            else if (e < 2050) stg(&ws[OFF_HS  + b*1025 + e - 1025], 0.0f);
            else if (e < 3075) stg(&ws[OFF_HS2 + b*1025 + e - 2050], 0.0f);
        }
        // stage x slab: rows 2sub,2sub+1 contiguous -> 2048 float4.
        {
            const float4* x4 = (const float4*)x;
            float4* sX4 = (float4*)sX;
            #pragma unroll
            for (int e = tid; e < 2048; e += 1024) {
                int c = e >> 5, off = e & 31;
                sX4[e] = x4[b*65536 + c*1024 + sub*32 + off];
            }
        }
        // stage W[c][f]: f<32 phi, f>=32 psi.
        #pragma unroll
        for (int e = tid; e < 4096; e += 1024) {
            int f = e >> 6, c = e & 63;
            sW[c*64 + f] = (f < 32) ? phi_w[f*64 + c] : psi_w[(f-32)*64 + c];
        }
        if (tid < 64) {
            float s = 0;
            for (int i = 0; i < 32; ++i) s += cp_w[i]*theta_w[i*64 + tid];
            sth[tid] = s;
        } else if (tid == 64) {
            float s = 0;
            for (int i = 0; i < 32; ++i) s += cp_w[i]*theta_b[i];
            sth[64] = s;
        }
        __syncthreads();   // staging done; drains vmcnt (counter zeros)
        if (bid == 0 && tid == 0) {    // publish ready flags (poison-proof)
            stgu(&bars[288], 0x5A5A5A5Au);
            stgu(&bars[289], 0xA5A5A5A5u);
        }
        const int pxl = tid & 63;      // pixel column
        const int fg  = tid >> 6;      // wave index = filter group (4 f)
        float tb = sth[64];
        float a00=0, a01=0, a02=0, a03=0;   // row 2sub,   filters fg*4..+3
        float a10=0, a11=0, a12=0, a13=0;   // row 2sub+1
        float th0 = tb, th1 = tb;           // theta (fg==0 wave only)
        const float4* sW4 = (const float4*)sW;
        #pragma unroll 8
        for (int c = 0; c < 64; ++c) {
            float x0 = sX[c*128 + pxl];
            float x1 = sX[c*128 + 64 + pxl];
            float4 w = sW4[c*16 + fg];      // wave-uniform: broadcast
            a00 += x0*w.x; a01 += x0*w.y; a02 += x0*w.z; a03 += x0*w.w;
            a10 += x1*w.x; a11 += x1*w.y; a12 += x1*w.z; a13 += x1*w.w;
            if (fg == 0) {                  // wave-uniform branch
                float st = sth[c];
                th0 += x0*st; th1 += x1*st;
            }
        }
        __syncthreads();   // conv reads done -> sX region reusable
        float* spsi = sh;          // 32 m x 33
        float* sphi = sh + 1056;
        float* sWw  = sh + 2112;
        // 2x2 pool: vertical max local, horizontal via shfl_xor(1).
        {
            float v0 = fmaxf(a00, a10), v1 = fmaxf(a01, a11);
            float v2 = fmaxf(a02, a12), v3 = fmaxf(a03, a13);
            float h0 = fmaxf(v0, __shfl_xor(v0, 1, 64));
            float h1 = fmaxf(v1, __shfl_xor(v1, 1, 64));
            float h2 = fmaxf(v2, __shfl_xor(v2, 1, 64));
            float h3 = fmaxf(v3, __shfl_xor(v3, 1, 64));
            if ((pxl & 1) == 0) {
                int ml = pxl >> 1;          // 0..31 pooled column
                int f0 = fg << 2;
                if (fg < 8) {               // phi filters
                    sphi[ml*33 + f0]     = h0 + phi_b[f0];
                    sphi[ml*33 + f0 + 1] = h1 + phi_b[f0 + 1];
                    sphi[ml*33 + f0 + 2] = h2 + phi_b[f0 + 2];
                    sphi[ml*33 + f0 + 3] = h3 + phi_b[f0 + 3];
                } else {                    // psi filters
                    int i0 = f0 - 32;
                    spsi[ml*33 + i0]     = h0 + psi_b[i0];
                    spsi[ml*33 + i0 + 1] = h1 + psi_b[i0 + 1];
                    spsi[ml*33 + i0 + 2] = h2 + psi_b[i0 + 2];
                    spsi[ml*33 + i0 + 3] = h3 + psi_b[i0 + 3];
                }
            }
        }
        if (fg == 0) {     // theta a: 2 pixels per lane, plain stores (kB)
            int nb = (b<<12) + (sub<<7);
            ws[OFF_A + nb + pxl]      = th0;
            ws[OFF_A + nb + 64 + pxl] = th1;
            sA2[pxl]      = th0;            // LDS: P2 reads these
            sA2[64 + pxl] = th1;
        }
        // stage Ww (64 o x 32 i, padded 33)
        #pragma unroll
        for (int e = tid; e < 2048; e += 1024)
            sWw[(e >> 5)*33 + (e & 31)] = Ww[(e >> 5)*33 + (e & 31)];
        __syncthreads();
        // bb reduce from sphi (sc1: read by P2 peers after gen1)
        {
            int ml = tid >> 5, il = tid & 31;
            float v = sphi[ml*33 + il] * cp_w[32 + il];
            v += __shfl_xor(v, 16, 32);
            v += __shfl_xor(v,  8, 32);
            v += __shfl_xor(v,  4, 32);
            v += __shfl_xor(v,  2, 32);
            v += __shfl_xor(v,  1, 32);
            if (il == 0)
                stg(&ws[OFF_BB + (b<<10) + (sub<<5) + ml], v);
        }
        // U-loop: PLAIN o-major stores (consumed only by kA2 post-boundary)
        #pragma unroll
        for (int rep = 0; rep < 2; ++rep) {
            int o  = (tid >> 5) + (rep << 5);   // 0..63
            int ml = tid & 31;
            const float* pr = &spsi[ml*33];
            const float* wr = &sWw[o*33];
            float u = 0;
            #pragma unroll
            for (int i2 = 0; i2 < 32; ++i2) u += pr[i2]*wr[i2];
            ws[OFF_U + (((b<<6) + o)<<10) + (sub<<5) + ml] = u;
        }
    }
    // gen1 (per-batch), with one-time ready-flag check before first RMW
    __syncthreads();
    if (tid == 0) {
        while ((ldgu(&bars[288]) ^ ldgu(&bars[289])) != 0xFFFFFFFFu)
            __builtin_amdgcn_s_sleep(2);
        unsigned* ctr = bars + ((b + 1) << 5);
        __hip_atomic_fetch_add(ctr, 1u, __ATOMIC_RELAXED,
                               __HIP_MEMORY_SCOPE_AGENT);
        while (ldgu(ctr) < 32u) __builtin_amdgcn_s_sleep(2);
    }
    __syncthreads();

    // ---------- Phase 2: rank bb -> RK, k_n per pixel, per-b histogram ----
    {
        float* sb = sh;
        sb[tid] = ldg1(&ws[OFF_BB + (b<<10) + tid]);
        __syncthreads();
        {   // rank 32 m's (32 lanes per m, integer-exact)
            int ml = tid >> 5, jl = tid & 31;
            int m = (sub << 5) + ml;
            float vv = sb[m];
            int cnt = 0;
            for (int s = 0; s < 32; ++s) {
                int j = jl + (s << 5);
                float u = sb[j];
                cnt += (u > vv || (u == vv && j < m)) ? 1 : 0;
            }
            cnt += __shfl_xor(cnt,  1, 32);
            cnt += __shfl_xor(cnt,  2, 32);
            cnt += __shfl_xor(cnt,  4, 32);
            cnt += __shfl_xor(cnt,  8, 32);
            cnt += __shfl_xor(cnt, 16, 32);
            if (jl == 0)
                ((int*)ws)[OFF_RK + (b<<10) + m] = cnt;   // plain: kA2
        }
        {   // k_n for 128 pixels (8 lanes/pixel) + hist atomics
            int l = tid >> 3, jl = tid & 7;
            int n = (sub << 7) + l;
            float av = sA2[l];
            float tt = -av;
            const float2* sb2 = (const float2*)sb;
            int cnt = 0;
            for (int s = 0; s < 64; ++s) {
                float2 u = sb2[jl + (s << 3)];
                cnt += (u.x > tt) ? 1 : 0;
                cnt += (u.y > tt) ? 1 : 0;
            }
            cnt += __shfl_xor(cnt, 1, 8);
            cnt += __shfl_xor(cnt, 2, 8);
            cnt += __shfl_xor(cnt, 4, 8);
            if (jl == 0) {
                ((int*)ws)[OFF_KK + (b<<12) + n] = cnt;   // plain: kB
                atomicAdd(&ws[OFF_HC + b*1025 + cnt], 1.0f);
                atomicAdd(&ws[OFF_HS + b*1025 + cnt], av);
                atomicAdd(&ws[OFF_HS2 + b*1025 + cnt], av*av);
            }
        }
    }
    // kernel ends; boundary = global sync before kA2.
}

// kA2 (= P3): sorted prefixes T1/T2 + BN moment partials. ALL loads plain
// (launch acquire invalidated L2 -> MALL-fresh); BB/RK/hist shared by 32
// blocks/batch -> L2 reuse. Block (b, og=sub): 2 output channels.
__global__ __launch_bounds__(1024) void kA2(float* __restrict__ ws)
{
    __shared__ float sh[6212];
    const int tid = threadIdx.x;
    const int b   = blockIdx.x >> 5;
    const int obase = (blockIdx.x & 31) << 1;
    float* ssb  = sh;
    float* sU0  = sh + 1024;
    float* sU1  = sh + 2048;
    float* shc  = sh + 3072;
    float* shs  = sh + 4097;
    float* shs2 = sh + 5122;
    float* swp1 = sh + 6148;
    float* swp2 = sh + 6180;
    {
        float bbv = ws[OFF_BB + (b<<10) + tid];
        int   rk  = ((const int*)ws)[OFF_RK + (b<<10) + tid];
        float u0  = ws[OFF_U + (((b<<6) + obase)<<10) + tid];
        float u1  = ws[OFF_U + (((b<<6) + obase + 1)<<10) + tid];
        ssb[rk] = bbv;
        sU0[rk] = u0;
        sU1[rk] = u1;
        shc[tid]  = ws[OFF_HC  + b*1025 + tid];
        shs[tid]  = ws[OFF_HS  + b*1025 + tid];
        shs2[tid] = ws[OFF_HS2 + b*1025 + tid];
        if (tid == 0) {
            shc[1024]  = ws[OFF_HC  + b*1025 + 1024];
            shs[1024]  = ws[OFF_HS  + b*1025 + 1024];
            shs2[1024] = ws[OFF_HS2 + b*1025 + 1024];
        }
    }
    __syncthreads();
    int ch = tid >> 1, o2 = tid & 1;
    int o  = obase + o2;
    int wv = tid >> 6, chl = (tid & 63) >> 1;
    const float* sU = o2 ? sU1 : sU0;
    float p[2], sp[2];
    float s1 = 0, s2 = 0;
    #pragma unroll
    for (int jl = 0; jl < 2; ++jl) {
        int jj = (ch<<1) + jl;
        float v = sU[jj];
        p[jl] = v;
        sp[jl] = ssb[jj]*v;
        s1 += v; s2 += sp[jl];
    }
    float own1 = s1, own2 = s2;
    #pragma unroll
    for (int d = 1; d < 32; d <<= 1) {
        float u1 = __shfl_up(s1, d<<1, 64);
        float u2 = __shfl_up(s2, d<<1, 64);
        if (chl >= d) { s1 += u1; s2 += u2; }
    }
    if (chl == 31) { swp1[(wv<<1)+o2] = s1; swp2[(wv<<1)+o2] = s2; }
    __syncthreads();
    float off1 = 0, off2 = 0;
    for (int w = 0; w < 16; ++w) {
        if (w < wv) { off1 += swp1[(w<<1)+o2]; off2 += swp2[(w<<1)+o2]; }
    }
    float run1 = off1 + s1 - own1;   // exclusive prefix before chunk ch
    float run2 = off2 + s2 - own2;
    float* T1 = ws + OFF_T1 + b*65600;
    float* T2 = ws + OFF_T2 + b*65600;
    if (ch == 0) { T1[o] = 0.0f; T2[o] = 0.0f; }
    const float inv = 1.0f/1024.0f;
    float m1 = 0, m2 = 0;
    #pragma unroll
    for (int jl = 0; jl < 2; ++jl) {
        int k = (ch<<1) + jl + 1;
        run1 += p[jl]; run2 += sp[jl];
        float t1 = run1*inv, t2 = run2*inv;
        T1[(k<<6) + o] = t1;        // plain o-major (L2 absorbs)
        T2[(k<<6) + o] = t2;
        float c = shc[k], sa_ = shs[k], sa2 = shs2[k];
        m1 += sa_*t1 + c*t2;
        m2 += (sa2*t1 + 2.0f*sa_*t2)*t1 + c*t2*t2;
    }
    m1 += __shfl_xor(m1,  2, 64); m2 += __shfl_xor(m2,  2, 64);
    m1 += __shfl_xor(m1,  4, 64); m2 += __shfl_xor(m2,  4, 64);
    m1 += __shfl_xor(m1,  8, 64); m2 += __shfl_xor(m2,  8, 64);
    m1 += __shfl_xor(m1, 16, 64); m2 += __shfl_xor(m2, 16, 64);
    m1 += __shfl_xor(m1, 32, 64); m2 += __shfl_xor(m2, 32, 64);
    __syncthreads();   // swp reuse
    if (chl == 0) { swp1[(wv<<1)+o2] = m1; swp2[(wv<<1)+o2] = m2; }
    __syncthreads();
    if (tid < 2) {
        float a1 = 0, a2 = 0;
        for (int w = 0; w < 16; ++w) {
            a1 += swp1[(w<<1)+tid]; a2 += swp2[(w<<1)+tid];
        }
        ws[OFF_MP1 + (b<<6) + obase + tid] = a1;   // plain: kB
        ws[OFF_MP2 + (b<<6) + obase + tid] = a2;
    }
}

// kB (= P4): r12 verbatim. out = A[o]*(a_n*T1[k_n,o]+T2[k_n,o])+D[o]+x.
__global__ __launch_bounds__(512) void kB(
    const float* __restrict__ x, const float* __restrict__ Wb,
    const float* __restrict__ gamma, const float* __restrict__ beta,
    const float* __restrict__ ws, float* __restrict__ out)
{
    __shared__ float tile[64*65];
    __shared__ float sa[64];
    __shared__ int   sk[64];
    __shared__ float sA[64];
    __shared__ float sD[64];
    const int tid = threadIdx.x;
    const int b   = blockIdx.x >> 6;
    const int n0  = (blockIdx.x & 63) << 6;
    if (tid < 64) {
        sa[tid] = ws[OFF_A + (b<<12) + n0 + tid];
        sk[tid] = ((const int*)ws)[OFF_KK + (b<<12) + n0 + tid];
        const float Ninv = 1.0f/32768.0f;
        float m1s = 0, m2s = 0;
        #pragma unroll
        for (int b3 = 0; b3 < 8; ++b3) {
            m1s += ws[OFF_MP1 + (b3<<6) + tid];
            m2s += ws[OFF_MP2 + (b3<<6) + tid];
        }
        float m1 = m1s * Ninv;
        float m2 = m2s * Ninv;
        float wb = Wb[tid];
        float mu  = m1 + wb;
        float E2  = m2 + 2.0f*wb*m1 + wb*wb;
        float var = E2 - mu*mu;
        float A = gamma[tid] * rsqrtf(var + 1e-5f);
        sA[tid] = A;
        sD[tid] = beta[tid] + A*(wb - mu);
    }
    __syncthreads();
    const float* T1 = ws + OFF_T1 + b*65600;
    const float* T2 = ws + OFF_T2 + b*65600;
    {
        int o = tid & 63, ng = tid >> 6;
        float Ao = sA[o], Do = sD[o];
        #pragma unroll
        for (int j = 0; j < 8; ++j) {
            int n = (ng << 3) + j;
            int k = sk[n];                 // wave-uniform -> coalesced 256B
            float a = sa[n];
            float t1 = T1[(k<<6) + o];
            float t2 = T2[(k<<6) + o];
            tile[o*65 + n] = Ao*(a*t1 + t2) + Do;
        }
    }
    __syncthreads();
    {
        int n = tid & 63, og = tid >> 6;
        #pragma unroll
        for (int j = 0; j < 8; ++j) {
            int o = (og << 3) + j;
            int idx = ((b<<6) + o)*4096 + n0 + n;
            out[idx] = tile[o*65 + n] + x[idx];
        }
    }
}

extern "C" void kernel_launch(void* const* d_in, const int* in_sizes, int n_in,
                              void* d_out, int out_size, void* d_ws, size_t ws_size,
                              hipStream_t stream)
{
    const float* x       = (const float*)d_in[0];
    const float* theta_w = (const float*)d_in[1];
    const float* theta_b = (const float*)d_in[2];
    const float* phi_w   = (const float*)d_in[3];
    const float* phi_b   = (const float*)d_in[4];
    const float* psi_w   = (const float*)d_in[5];
    const float* psi_b   = (const float*)d_in[6];
    const float* cp_w    = (const float*)d_in[7];
    const float* Ww      = (const float*)d_in[8];
    const float* Wb      = (const float*)d_in[9];
    const float* gamma   = (const float*)d_in[10];
    const float* beta    = (const float*)d_in[11];
    float* ws  = (float*)d_ws;
    float* out = (float*)d_out;

    kA1<<<256, 1024, 0, stream>>>(x, theta_w, theta_b, phi_w, phi_b,
                                  psi_w, psi_b, cp_w, Ww, ws);
    kA2<<<256, 1024, 0, stream>>>(ws);
    kB<<<512, 512, 0, stream>>>(x, Wb, gamma, beta, ws, out);
}

// Round 14
// 116.193 us; speedup vs baseline: 1.0166x; 1.0166x over previous
//
#include <hip/hip_runtime.h>

// B=8, C=64, H=W=64, CI=32, N=4096 pixels, M=1024 pooled.
// y[b,n,:] = (a_n*S1[k_n,:] + S2[k_n,:])/1024 ; only W_w . y is needed, so
// track U = Ww.psi (64-dim) and its sorted-order prefixes T1/T2 directly.
// BN stats from per-k scalars (cnt, sum a, sum a^2) x T rows - no Gram.
//
// r19: r12 (best, 115.7) + store/poll per-batch barriers. r13's split
// proved P3~8us and P1+gen1+P2 ~26-28us vs a ~10us work model; the
// largest identified unmodeled cost is barrier ARRIVAL serialization:
// 32 cross-XCD RMWs on one line ~= 3.2us per barrier x2. Never isolated
// post-fence-era (r8 tree test was fence-masked; r5 store/poll drowned
// in 4-line global poll traffic). New arrival: one relaxed sc1 STORE of
// gen into the block's own slot (32 slots = one 128B line per batch,
// parallel); detection: wave0 lane l polls slot (l&31), __all(v>=gen) --
// one line per poll round. Flag-gated first poll (poison slots >= 1
// would false-trigger). All else byte-identical to r12.
#define OFF_A    0         // a[b][n]               : 32768 floats
#define OFF_BB   32768     // bb[b][m]              : 8192
#define OFF_RK   40960     // rank[b][m] (int)      : 8192
#define OFF_U    57344     // U_T[b][o][m]          : 8*64*1024 = 524288
#define OFF_T1   581632    // T1[b][k<=1024][o]     : 8*1025*64 = 524800
#define OFF_T2   1106432   // T2[b][k][o]           : 524800
#define OFF_KK   1631232   // k[b][n] (int)         : 32768
#define OFF_MP1  1664000   // moment1 partials [b][o] : 512
#define OFF_MP2  1664512   // moment2 partials [b][o] : 512
#define OFF_HC   1665024   // hist cnt[b][1025]     : 8200
#define OFF_HS   1673224   // hist sum_a[b][1025]   : 8200
#define OFF_HS2  1681424   // hist sum_a2[b][1025]  : 8200
#define OFF_BAR  1689632   // 128B-aligned: slots[b*32+sub] 256 u32;
                           // flags @ [256],[257]

// Coherent (sc1, L2-bypass) helpers -- intra-kA cross-block data only.
__device__ __forceinline__ void stg(float* p, float v) {
    __hip_atomic_store(p, v, __ATOMIC_RELAXED, __HIP_MEMORY_SCOPE_AGENT);
}
__device__ __forceinline__ float ldg1(const float* p) {
    return __hip_atomic_load(p, __ATOMIC_RELAXED, __HIP_MEMORY_SCOPE_AGENT);
}
__device__ __forceinline__ void stgi(int* p, int v) {
    __hip_atomic_store(p, v, __ATOMIC_RELAXED, __HIP_MEMORY_SCOPE_AGENT);
}
__device__ __forceinline__ int ldgi(const int* p) {
    return __hip_atomic_load(p, __ATOMIC_RELAXED, __HIP_MEMORY_SCOPE_AGENT);
}
__device__ __forceinline__ void stgu(unsigned* p, unsigned v) {
    __hip_atomic_store(p, v, __ATOMIC_RELAXED, __HIP_MEMORY_SCOPE_AGENT);
}
__device__ __forceinline__ unsigned ldgu(const unsigned* p) {
    return __hip_atomic_load(p, __ATOMIC_RELAXED, __HIP_MEMORY_SCOPE_AGENT);
}

// kA LDS carve (floats), sh[12484] = 49.9 KB:
// P1 conv:  sX@0 (64c x 128px = 8192) sW@8192 (64c x 64f = 4096)
//           sth@12288 (68)  sA2@12356 (128, persists into P2)
// P1 epilo: spsi@0 (32x33) sphi@1056 (32x33) sWw@2112 (64x33) [sX dead]
// P2:       sb@0 (1024)
// P3:       ssb@0 sU0@1024 sU1@2048 shc@3072 shs@4097 shs2@5122
//           swp1@6148 swp2@6180
__global__ __launch_bounds__(1024) void kA(
    const float* __restrict__ x, const float* __restrict__ theta_w,
    const float* __restrict__ theta_b, const float* __restrict__ phi_w,
    const float* __restrict__ phi_b, const float* __restrict__ psi_w,
    const float* __restrict__ psi_b, const float* __restrict__ cp_w,
    const float* __restrict__ Ww, float* __restrict__ ws)
{
    __shared__ __align__(16) float sh[12484];
    const int tid = threadIdx.x;
    const int bid = blockIdx.x;
    const int b   = bid >> 5;     // 32 blocks per batch image
    const int sub = bid & 31;
    unsigned* slots = (unsigned*)(ws + OFF_BAR);
    float* sX  = sh;
    float* sW  = sh + 8192;
    float* sth = sh + 12288;
    float* sA2 = sh + 12356;

    // ---------- Phase 1: conv (GEMM form) + pool -> bb, U_T ; theta -> a --
    {
        if (bid == 0 && tid < 256)      // zero all arrival slots (sc1)
            stgu(&slots[tid], 0u);
        // zero this block's slice of ITS OWN batch's hist (sc1: target of
        // P2's MALL atomics)
        if (tid < 97) {
            int e = sub*97 + tid;
            if (e < 1025)      stg(&ws[OFF_HC  + b*1025 + e], 0.0f);
            else if (e < 2050) stg(&ws[OFF_HS  + b*1025 + e - 1025], 0.0f);
            else if (e < 3075) stg(&ws[OFF_HS2 + b*1025 + e - 2050], 0.0f);
        }
        // stage x slab: rows 2sub,2sub+1 contiguous -> 2048 float4.
        {
            const float4* x4 = (const float4*)x;
            float4* sX4 = (float4*)sX;
            #pragma unroll
            for (int e = tid; e < 2048; e += 1024) {
                int c = e >> 5, off = e & 31;
                sX4[e] = x4[b*65536 + c*1024 + sub*32 + off];
            }
        }
        // stage W[c][f]: f<32 phi, f>=32 psi.
        #pragma unroll
        for (int e = tid; e < 4096; e += 1024) {
            int f = e >> 6, c = e & 63;
            sW[c*64 + f] = (f < 32) ? phi_w[f*64 + c] : psi_w[(f-32)*64 + c];
        }
        if (tid < 64) {
            float s = 0;
            for (int i = 0; i < 32; ++i) s += cp_w[i]*theta_w[i*64 + tid];
            sth[tid] = s;
        } else if (tid == 64) {
            float s = 0;
            for (int i = 0; i < 32; ++i) s += cp_w[i]*theta_b[i];
            sth[64] = s;
        }
        __syncthreads();   // staging done; drains vmcnt (slot zeros at MALL)
        if (bid == 0 && tid == 0) {    // publish ready flags (poison-proof)
            stgu(&slots[256], 0x5A5A5A5Au);
            stgu(&slots[257], 0xA5A5A5A5u);
        }
        const int pxl = tid & 63;      // pixel column
        const int fg  = tid >> 6;      // wave index = filter group (4 f)
        float tb = sth[64];
        float a00=0, a01=0, a02=0, a03=0;   // row 2sub,   filters fg*4..+3
        float a10=0, a11=0, a12=0, a13=0;   // row 2sub+1
        float th0 = tb, th1 = tb;           // theta (fg==0 wave only)
        const float4* sW4 = (const float4*)sW;
        #pragma unroll 8
        for (int c = 0; c < 64; ++c) {
            float x0 = sX[c*128 + pxl];
            float x1 = sX[c*128 + 64 + pxl];
            float4 w = sW4[c*16 + fg];      // wave-uniform: broadcast
            a00 += x0*w.x; a01 += x0*w.y; a02 += x0*w.z; a03 += x0*w.w;
            a10 += x1*w.x; a11 += x1*w.y; a12 += x1*w.z; a13 += x1*w.w;
            if (fg == 0) {                  // wave-uniform branch
                float st = sth[c];
                th0 += x0*st; th1 += x1*st;
            }
        }
        __syncthreads();   // conv reads done -> sX region reusable
        float* spsi = sh;          // 32 m x 33
        float* sphi = sh + 1056;
        float* sWw  = sh + 2112;
        // 2x2 pool: vertical max local, horizontal via shfl_xor(1).
        {
            float v0 = fmaxf(a00, a10), v1 = fmaxf(a01, a11);
            float v2 = fmaxf(a02, a12), v3 = fmaxf(a03, a13);
            float h0 = fmaxf(v0, __shfl_xor(v0, 1, 64));
            float h1 = fmaxf(v1, __shfl_xor(v1, 1, 64));
            float h2 = fmaxf(v2, __shfl_xor(v2, 1, 64));
            float h3 = fmaxf(v3, __shfl_xor(v3, 1, 64));
            if ((pxl & 1) == 0) {
                int ml = pxl >> 1;          // 0..31 pooled column
                int f0 = fg << 2;
                if (fg < 8) {               // phi filters
                    sphi[ml*33 + f0]     = h0 + phi_b[f0];
                    sphi[ml*33 + f0 + 1] = h1 + phi_b[f0 + 1];
                    sphi[ml*33 + f0 + 2] = h2 + phi_b[f0 + 2];
                    sphi[ml*33 + f0 + 3] = h3 + phi_b[f0 + 3];
                } else {                    // psi filters
                    int i0 = f0 - 32;
                    spsi[ml*33 + i0]     = h0 + psi_b[i0];
                    spsi[ml*33 + i0 + 1] = h1 + psi_b[i0 + 1];
                    spsi[ml*33 + i0 + 2] = h2 + psi_b[i0 + 2];
                    spsi[ml*33 + i0 + 3] = h3 + psi_b[i0 + 3];
                }
            }
        }
        if (fg == 0) {     // theta a: 2 pixels per lane, plain stores (kB)
            int nb = (b<<12) + (sub<<7);
            ws[OFF_A + nb + pxl]      = th0;
            ws[OFF_A + nb + 64 + pxl] = th1;
            sA2[pxl]      = th0;            // LDS: P2 reads these
            sA2[64 + pxl] = th1;
        }
        // stage Ww (64 o x 32 i, padded 33)
        #pragma unroll
        for (int e = tid; e < 2048; e += 1024)
            sWw[(e >> 5)*33 + (e & 31)] = Ww[(e >> 5)*33 + (e & 31)];
        __syncthreads();
        // bb reduce from sphi (sc1: read by P2 peers after gen1)
        {
            int ml = tid >> 5, il = tid & 31;
            float v = sphi[ml*33 + il] * cp_w[32 + il];
            v += __shfl_xor(v, 16, 32);
            v += __shfl_xor(v,  8, 32);
            v += __shfl_xor(v,  4, 32);
            v += __shfl_xor(v,  2, 32);
            v += __shfl_xor(v,  1, 32);
            if (il == 0)
                stg(&ws[OFF_BB + (b<<10) + (sub<<5) + ml], v);
        }
        // U-loop: o-major sc1 stores (read by P3 cross-block, same kernel)
        #pragma unroll
        for (int rep = 0; rep < 2; ++rep) {
            int o  = (tid >> 5) + (rep << 5);   // 0..63
            int ml = tid & 31;
            const float* pr = &spsi[ml*33];
            const float* wr = &sWw[o*33];
            float u = 0;
            #pragma unroll
            for (int i2 = 0; i2 < 32; ++i2) u += pr[i2]*wr[i2];
            stg(&ws[OFF_U + (((b<<6) + o)<<10) + (sub<<5) + ml], u);
        }
    }
    // gen1 (per-batch): flag-gated store/poll. Arrival = one sc1 store
    // into own slot (parallel across 32 blocks, one 128B line per batch);
    // wave0 lane l polls slot (l&31). vmcnt drain at the __syncthreads
    // is the release (r9-validated model).
    __syncthreads();
    if (tid < 64) {
        while ((ldgu(&slots[256]) ^ ldgu(&slots[257])) != 0xFFFFFFFFu)
            __builtin_amdgcn_s_sleep(2);
        if (tid == 0) stgu(&slots[(b<<5) + sub], 1u);
        for (;;) {
            unsigned v = ldgu(&slots[(b<<5) + (tid & 31)]);
            if (__all(v >= 1u)) break;
            __builtin_amdgcn_s_sleep(2);
        }
    }
    __syncthreads();

    // ---------- Phase 2: rank bb -> RK, k_n per pixel, per-b histogram ----
    {
        float* sb = sh;
        sb[tid] = ldg1(&ws[OFF_BB + (b<<10) + tid]);
        __syncthreads();
        {   // rank 32 m's (32 lanes per m, integer-exact)
            int ml = tid >> 5, jl = tid & 31;
            int m = (sub << 5) + ml;
            float vv = sb[m];
            int cnt = 0;
            for (int s = 0; s < 32; ++s) {
                int j = jl + (s << 5);
                float u = sb[j];
                cnt += (u > vv || (u == vv && j < m)) ? 1 : 0;
            }
            cnt += __shfl_xor(cnt,  1, 32);
            cnt += __shfl_xor(cnt,  2, 32);
            cnt += __shfl_xor(cnt,  4, 32);
            cnt += __shfl_xor(cnt,  8, 32);
            cnt += __shfl_xor(cnt, 16, 32);
            if (jl == 0)
                stgi(&((int*)ws)[OFF_RK + (b<<10) + m], cnt);  // sc1: P3
        }
        {   // k_n for 128 pixels (8 lanes/pixel) + hist atomics
            int l = tid >> 3, jl = tid & 7;
            int n = (sub << 7) + l;
            float av = sA2[l];
            float tt = -av;
            const float2* sb2 = (const float2*)sb;
            int cnt = 0;
            for (int s = 0; s < 64; ++s) {
                float2 u = sb2[jl + (s << 3)];
                cnt += (u.x > tt) ? 1 : 0;
                cnt += (u.y > tt) ? 1 : 0;
            }
            cnt += __shfl_xor(cnt, 1, 8);
            cnt += __shfl_xor(cnt, 2, 8);
            cnt += __shfl_xor(cnt, 4, 8);
            if (jl == 0) {
                ((int*)ws)[OFF_KK + (b<<12) + n] = cnt;   // plain: kB only
                atomicAdd(&ws[OFF_HC + b*1025 + cnt], 1.0f);
                atomicAdd(&ws[OFF_HS + b*1025 + cnt], av);
                atomicAdd(&ws[OFF_HS2 + b*1025 + cnt], av*av);
            }
        }
    }
    // gen2 (per-batch): store/poll, no flag gate needed (post-gen1).
    __syncthreads();
    if (tid < 64) {
        if (tid == 0) stgu(&slots[(b<<5) + sub], 2u);
        for (;;) {
            unsigned v = ldgu(&slots[(b<<5) + (tid & 31)]);
            if (__all(v >= 2u)) break;
            __builtin_amdgcn_s_sleep(2);
        }
    }
    __syncthreads();

    // ---------- Phase 3: sorted prefixes T1/T2 + BN moments (r12 verbatim)
    {
        const int obase = sub << 1;
        float* ssb  = sh;
        float* sU0  = sh + 1024;
        float* sU1  = sh + 2048;
        float* shc  = sh + 3072;
        float* shs  = sh + 4097;
        float* shs2 = sh + 5122;
        float* swp1 = sh + 6148;
        float* swp2 = sh + 6180;
        {
            float bbv = ldg1(&ws[OFF_BB + (b<<10) + tid]);
            int   rk  = ldgi(&((const int*)ws)[OFF_RK + (b<<10) + tid]);
            float u0  = ldg1(&ws[OFF_U + (((b<<6) + obase)<<10) + tid]);
            float u1  = ldg1(&ws[OFF_U + (((b<<6) + obase + 1)<<10) + tid]);
            ssb[rk] = bbv;
            sU0[rk] = u0;
            sU1[rk] = u1;
            shc[tid]  = ldg1(&ws[OFF_HC  + b*1025 + tid]);
            shs[tid]  = ldg1(&ws[OFF_HS  + b*1025 + tid]);
            shs2[tid] = ldg1(&ws[OFF_HS2 + b*1025 + tid]);
            if (tid == 0) {
                shc[1024]  = ldg1(&ws[OFF_HC  + b*1025 + 1024]);
                shs[1024]  = ldg1(&ws[OFF_HS  + b*1025 + 1024]);
                shs2[1024] = ldg1(&ws[OFF_HS2 + b*1025 + 1024]);
            }
        }
        __syncthreads();
        int ch = tid >> 1, o2 = tid & 1;
        int o  = obase + o2;
        int wv = tid >> 6, chl = (tid & 63) >> 1;
        const float* sU = o2 ? sU1 : sU0;
        float p[2], sp[2];
        float s1 = 0, s2 = 0;
        #pragma unroll
        for (int jl = 0; jl < 2; ++jl) {
            int jj = (ch<<1) + jl;
            float v = sU[jj];
            p[jl] = v;
            sp[jl] = ssb[jj]*v;
            s1 += v; s2 += sp[jl];
        }
        float own1 = s1, own2 = s2;
        #pragma unroll
        for (int d = 1; d < 32; d <<= 1) {
            float u1 = __shfl_up(s1, d<<1, 64);
            float u2 = __shfl_up(s2, d<<1, 64);
            if (chl >= d) { s1 += u1; s2 += u2; }
        }
        if (chl == 31) { swp1[(wv<<1)+o2] = s1; swp2[(wv<<1)+o2] = s2; }
        __syncthreads();
        float off1 = 0, off2 = 0;
        for (int w = 0; w < 16; ++w) {
            if (w < wv) { off1 += swp1[(w<<1)+o2]; off2 += swp2[(w<<1)+o2]; }
        }
        float run1 = off1 + s1 - own1;
        float run2 = off2 + s2 - own2;
        float* T1 = ws + OFF_T1 + b*65600;
        float* T2 = ws + OFF_T2 + b*65600;
        if (ch == 0) { T1[o] = 0.0f; T2[o] = 0.0f; }
        const float inv = 1.0f/1024.0f;
        float m1 = 0, m2 = 0;
        #pragma unroll
        for (int jl = 0; jl < 2; ++jl) {
            int k = (ch<<1) + jl + 1;
            run1 += p[jl]; run2 += sp[jl];
            float t1 = run1*inv, t2 = run2*inv;
            T1[(k<<6) + o] = t1;        // plain o-major (L2 absorbs)
            T2[(k<<6) + o] = t2;
            float c = shc[k], sa_ = shs[k], sa2 = shs2[k];
            m1 += sa_*t1 + c*t2;
            m2 += (sa2*t1 + 2.0f*sa_*t2)*t1 + c*t2*t2;
        }
        m1 += __shfl_xor(m1,  2, 64); m2 += __shfl_xor(m2,  2, 64);
        m1 += __shfl_xor(m1,  4, 64); m2 += __shfl_xor(m2,  4, 64);
        m1 += __shfl_xor(m1,  8, 64); m2 += __shfl_xor(m2,  8, 64);
        m1 += __shfl_xor(m1, 16, 64); m2 += __shfl_xor(m2, 16, 64);
        m1 += __shfl_xor(m1, 32, 64); m2 += __shfl_xor(m2, 32, 64);
        __syncthreads();
        if (chl == 0) { swp1[(wv<<1)+o2] = m1; swp2[(wv<<1)+o2] = m2; }
        __syncthreads();
        if (tid < 2) {
            float a1 = 0, a2 = 0;
            for (int w = 0; w < 16; ++w) {
                a1 += swp1[(w<<1)+tid]; a2 += swp2[(w<<1)+tid];
            }
            ws[OFF_MP1 + (b<<6) + obase + tid] = a1;
            ws[OFF_MP2 + (b<<6) + obase + tid] = a2;
        }
    }
}

// kB (= P4): r12 verbatim. out = A[o]*(a_n*T1[k_n,o]+T2[k_n,o])+D[o]+x.
__global__ __launch_bounds__(512) void kB(
    const float* __restrict__ x, const float* __restrict__ Wb,
    const float* __restrict__ gamma, const float* __restrict__ beta,
    const float* __restrict__ ws, float* __restrict__ out)
{
    __shared__ float tile[64*65];
    __shared__ float sa[64];
    __shared__ int   sk[64];
    __shared__ float sA[64];
    __shared__ float sD[64];
    const int tid = threadIdx.x;
    const int b   = blockIdx.x >> 6;
    const int n0  = (blockIdx.x & 63) << 6;
    if (tid < 64) {
        sa[tid] = ws[OFF_A + (b<<12) + n0 + tid];
        sk[tid] = ((const int*)ws)[OFF_KK + (b<<12) + n0 + tid];
        const float Ninv = 1.0f/32768.0f;
        float m1s = 0, m2s = 0;
        #pragma unroll
        for (int b3 = 0; b3 < 8; ++b3) {
            m1s += ws[OFF_MP1 + (b3<<6) + tid];
            m2s += ws[OFF_MP2 + (b3<<6) + tid];
        }
        float m1 = m1s * Ninv;
        float m2 = m2s * Ninv;
        float wb = Wb[tid];
        float mu  = m1 + wb;
        float E2  = m2 + 2.0f*wb*m1 + wb*wb;
        float var = E2 - mu*mu;
        float A = gamma[tid] * rsqrtf(var + 1e-5f);
        sA[tid] = A;
        sD[tid] = beta[tid] + A*(wb - mu);
    }
    __syncthreads();
    const float* T1 = ws + OFF_T1 + b*65600;
    const float* T2 = ws + OFF_T2 + b*65600;
    {
        int o = tid & 63, ng = tid >> 6;
        float Ao = sA[o], Do = sD[o];
        #pragma unroll
        for (int j = 0; j < 8; ++j) {
            int n = (ng << 3) + j;
            int k = sk[n];                 // wave-uniform -> coalesced 256B
            float a = sa[n];
            float t1 = T1[(k<<6) + o];
            float t2 = T2[(k<<6) + o];
            tile[o*65 + n] = Ao*(a*t1 + t2) + Do;
        }
    }
    __syncthreads();
    {
        int n = tid & 63, og = tid >> 6;
        #pragma unroll
        for (int j = 0; j < 8; ++j) {
            int o = (og << 3) + j;
            int idx = ((b<<6) + o)*4096 + n0 + n;
            out[idx] = tile[o*65 + n] + x[idx];
        }
    }
}

extern "C" void kernel_launch(void* const* d_in, const int* in_sizes, int n_in,
                              void* d_out, int out_size, void* d_ws, size_t ws_size,
                              hipStream_t stream)
{
    const float* x       = (const float*)d_in[0];
    const float* theta_w = (const float*)d_in[1];
    const float* theta_b = (const float*)d_in[2];
    const float* phi_w   = (const float*)d_in[3];
    const float* phi_b   = (const float*)d_in[4];
    const float* psi_w   = (const float*)d_in[5];
    const float* psi_b   = (const float*)d_in[6];
    const float* cp_w    = (const float*)d_in[7];
    const float* Ww      = (const float*)d_in[8];
    const float* Wb      = (const float*)d_in[9];
    const float* gamma   = (const float*)d_in[10];
    const float* beta    = (const float*)d_in[11];
    float* ws  = (float*)d_ws;
    float* out = (float*)d_out;

    kA<<<256, 1024, 0, stream>>>(x, theta_w, theta_b, phi_w, phi_b,
                                 psi_w, psi_b, cp_w, Ww, ws);
    kB<<<512, 512, 0, stream>>>(x, Wb, gamma, beta, ws, out);
}